// Round 4
// baseline (578.128 us; speedup 1.0000x reference)
//
#include <hip/hip_runtime.h>
#include <hip/hip_fp16.h>

// GDE func: out = MLP(relu(mean_agg(z,edges)@Wg + z@Ws + bg))
// Round 3 -> 4: separate GEMMs (HBM round-trips + vmcnt-drain starvation at
// 20% occupancy) replaced by TWO FUSED MLP kernels working on 128-row panels:
//   mlp_a: h2 = tanh( relu(Xc@Wgs^T + bg) @ W1 + b1 )   (h1 in 32KB swizzled LDS)
//   mlp_b: out = tanh(h2@W2 + b2) @ W3 + b3             (h3 col-blocks in LDS,
//                                                        L4 acc persists in regs)
// A/B fragments load straight from global (weights are L2-hot, 1.7MB total);
// no LDS staging of operands, no barrier-drain per K-step.

typedef _Float16 f16;
typedef __attribute__((ext_vector_type(8))) _Float16 f16x8;
typedef __attribute__((ext_vector_type(4))) float f32x4;

__device__ __forceinline__ float fast_tanh(float x) {
  float a = fabsf(x);
  float e = __expf(-2.0f * a);
  float r = (1.0f - e) * __builtin_amdgcn_rcpf(1.0f + e);
  return copysignf(r, x);
}

// XOR-swizzled byte offset for a [128][128] f16 LDS panel (row stride 256B).
// Spreads 8 consecutive rows across 8 distinct 16B slots -> conflict-free
// ds_read_b128 by 16 rows (2-way residual = free). Same map on write & read.
__device__ __forceinline__ int swz(int row, int col2) {
  return row * 256 + (col2 ^ ((row & 7) << 4));
}

__global__ __launch_bounds__(256) void zero_kernel(int* __restrict__ p, int n) {
  int i = blockIdx.x * 256 + threadIdx.x;
  int stride = gridDim.x * 256;
  for (; i < n; i += stride) p[i] = 0;
}

// ---- CSR build ----
__global__ __launch_bounds__(256) void deg_count(const int* __restrict__ dst,
                                                 int* __restrict__ degi, int E) {
  int e = blockIdx.x * 256 + threadIdx.x;
  if (e < E) atomicAdd(&degi[dst[e]], 1);
}

__global__ __launch_bounds__(256) void scan_partial(const int* __restrict__ degi,
                                                    int* __restrict__ bsum, int N) {
  __shared__ int lds[256];
  int b = blockIdx.x, t = threadIdx.x;
  int s = 0;
#pragma unroll
  for (int j = 0; j < 4; ++j) {
    int idx = b * 1024 + t * 4 + j;
    if (idx < N) s += degi[idx];
  }
  lds[t] = s;
  __syncthreads();
  for (int off = 128; off > 0; off >>= 1) {
    if (t < off) lds[t] += lds[t + off];
    __syncthreads();
  }
  if (t == 0) bsum[b] = lds[0];
}

__global__ void scan_bsums(const int* __restrict__ bsum, int* __restrict__ boff,
                           int* __restrict__ row_start, int nb, int N) {
  if (threadIdx.x == 0 && blockIdx.x == 0) {
    int acc = 0;
    for (int i = 0; i < nb; ++i) { boff[i] = acc; acc += bsum[i]; }
    row_start[N] = acc;  // == E
  }
}

__global__ __launch_bounds__(256) void scan_final(
    const int* __restrict__ degi, const int* __restrict__ boff,
    int* __restrict__ row_start, int* __restrict__ cursor, int N) {
  __shared__ int lds[256];
  int b = blockIdx.x, t = threadIdx.x;
  int base = b * 1024;
  int v[4];
  int s = 0;
#pragma unroll
  for (int j = 0; j < 4; ++j) {
    int idx = base + t * 4 + j;
    v[j] = (idx < N) ? degi[idx] : 0;
    s += v[j];
  }
  lds[t] = s;
  __syncthreads();
  for (int off = 1; off < 256; off <<= 1) {
    int x = lds[t];
    int y = (t >= off) ? lds[t - off] : 0;
    __syncthreads();
    lds[t] = x + y;
    __syncthreads();
  }
  int pre = boff[b] + lds[t] - s;
#pragma unroll
  for (int j = 0; j < 4; ++j) {
    int idx = base + t * 4 + j;
    if (idx < N) { row_start[idx] = pre; cursor[idx] = pre; pre += v[j]; }
  }
}

__global__ __launch_bounds__(256) void fill_adj(const int* __restrict__ src,
                                                const int* __restrict__ dst,
                                                int* __restrict__ cursor,
                                                int* __restrict__ adj, int E) {
  int e = blockIdx.x * 256 + threadIdx.x;
  if (e >= E) return;
  int p = atomicAdd(&cursor[dst[e]], 1);
  adj[p] = src[e];
}

// ---- fused gather + mean + Xcat: one 64-lane wave per node ----
__global__ __launch_bounds__(256) void gather_xcat(
    const float* __restrict__ z, const int* __restrict__ row_start,
    const int* __restrict__ adj, f16* __restrict__ Xc, int N) {
  int wave = (blockIdx.x * 256 + threadIdx.x) >> 6;
  int lane = threadIdx.x & 63;
  if (wave >= N) return;
  int n = wave;
  int beg = row_start[n], end = row_start[n + 1];
  float a0 = 0.0f, a1 = 0.0f;
  for (int i = beg; i < end; ++i) {
    int s = adj[i];
    const float* zp = z + (long long)s * 128;
    a0 += zp[lane];
    a1 += zp[lane + 64];
  }
  int dg = end - beg;
  float inv = 1.0f / (float)(dg > 1 ? dg : 1);
  long long o = (long long)n * 256;
  Xc[o + lane] = (f16)(a0 * inv);
  Xc[o + 64 + lane] = (f16)(a1 * inv);
  const float* zn = z + (long long)n * 128;
  Xc[o + 128 + lane] = (f16)zn[lane];
  Xc[o + 192 + lane] = (f16)zn[lane + 64];
}

// ---- weight prep (all Wt stored [ncol][K] row-major f16) ----
__global__ __launch_bounds__(256) void build_wgs(
    const float* __restrict__ Wg, const float* __restrict__ Ws, f16* __restrict__ Wt) {
  int i = blockIdx.x * 256 + threadIdx.x;
  if (i >= 128 * 256) return;
  int n = i >> 8, k = i & 255;
  float v = (k < 128) ? Wg[k * 128 + n] : Ws[(k - 128) * 128 + n];
  Wt[i] = (f16)v;
}

__global__ __launch_bounds__(256) void transpose_cast(
    const float* __restrict__ W, f16* __restrict__ Wt, int K, int N) {
  int i = blockIdx.x * 256 + threadIdx.x;
  if (i >= K * N) return;
  int n = i / K, k = i - n * K;
  Wt[i] = (f16)W[k * N + n];
}

// ---------------- fused MLP kernel A: L1 + L2 ----------------
// h2[Mpad,512] = tanh( relu(Xc[Mpad,256] @ wgs^T + bg) @ wt1^T + b1 )
// 4 waves as 2x2 over the 128x128 (or per-colblock) output tile.
// A-frag lane l: row l&15, k (l>>4)*8.. ; D: row (l>>4)*4+r, col l&15.
__global__ __launch_bounds__(256, 3) void mlp_a(
    const f16* __restrict__ Xc, const f16* __restrict__ wgs,
    const f16* __restrict__ wt1, const float* __restrict__ bg,
    const float* __restrict__ b1, f16* __restrict__ h2) {
  __shared__ __align__(16) char H1[128 * 256];  // 32KB swizzled f16 [128][128]

  const int tid = threadIdx.x;
  const int lane = tid & 63, wid = tid >> 6;
  const int wm = wid & 1, wn = wid >> 1;
  const int lr = lane & 15, lq = lane >> 4;
  const long long m0 = (long long)blockIdx.x * 128;

  // ---- L1: h1 = relu(Xc @ wgs^T + bg), out 128x128 ----
  {
    f32x4 acc[4][4];
#pragma unroll
    for (int i = 0; i < 4; ++i)
#pragma unroll
      for (int j = 0; j < 4; ++j)
#pragma unroll
        for (int r = 0; r < 4; ++r) acc[i][j][r] = 0.0f;

#pragma unroll
    for (int k0 = 0; k0 < 256; k0 += 32) {
      f16x8 a[4], b[4];
#pragma unroll
      for (int i = 0; i < 4; ++i)
        a[i] = *reinterpret_cast<const f16x8*>(
            Xc + (m0 + wm * 64 + i * 16 + lr) * 256 + k0 + lq * 8);
#pragma unroll
      for (int j = 0; j < 4; ++j)
        b[j] = *reinterpret_cast<const f16x8*>(
            wgs + (wn * 64 + j * 16 + lr) * 256 + k0 + lq * 8);
#pragma unroll
      for (int i = 0; i < 4; ++i)
#pragma unroll
        for (int j = 0; j < 4; ++j)
          acc[i][j] = __builtin_amdgcn_mfma_f32_16x16x32_f16(a[i], b[j], acc[i][j], 0, 0, 0);
    }
#pragma unroll
    for (int i = 0; i < 4; ++i)
#pragma unroll
      for (int j = 0; j < 4; ++j) {
        int col = wn * 64 + j * 16 + lr;
        float bv = bg[col];
#pragma unroll
        for (int r = 0; r < 4; ++r) {
          int row = wm * 64 + i * 16 + lq * 4 + r;
          float v = fmaxf(acc[i][j][r] + bv, 0.0f);
          *reinterpret_cast<f16*>(H1 + swz(row, col * 2)) = (f16)v;
        }
      }
  }
  __syncthreads();

  // ---- L2: h2 = tanh(h1 @ wt1^T + b1), 4 col-blocks of 128 ----
#pragma unroll 1
  for (int cb = 0; cb < 4; ++cb) {
    f32x4 acc[4][4];
#pragma unroll
    for (int i = 0; i < 4; ++i)
#pragma unroll
      for (int j = 0; j < 4; ++j)
#pragma unroll
        for (int r = 0; r < 4; ++r) acc[i][j][r] = 0.0f;

#pragma unroll
    for (int k0 = 0; k0 < 128; k0 += 32) {
      f16x8 a[4], b[4];
#pragma unroll
      for (int i = 0; i < 4; ++i)
        a[i] = *reinterpret_cast<const f16x8*>(
            H1 + swz(wm * 64 + i * 16 + lr, (k0 + lq * 8) * 2));
#pragma unroll
      for (int j = 0; j < 4; ++j)
        b[j] = *reinterpret_cast<const f16x8*>(
            wt1 + (cb * 128 + wn * 64 + j * 16 + lr) * 128 + k0 + lq * 8);
#pragma unroll
      for (int i = 0; i < 4; ++i)
#pragma unroll
        for (int j = 0; j < 4; ++j)
          acc[i][j] = __builtin_amdgcn_mfma_f32_16x16x32_f16(a[i], b[j], acc[i][j], 0, 0, 0);
    }
#pragma unroll
    for (int i = 0; i < 4; ++i)
#pragma unroll
      for (int j = 0; j < 4; ++j) {
        int colg = cb * 128 + wn * 64 + j * 16 + lr;
        float bv = b1[colg];
#pragma unroll
        for (int r = 0; r < 4; ++r) {
          long long row = m0 + wm * 64 + i * 16 + lq * 4 + r;
          h2[row * 512 + colg] = (f16)fast_tanh(acc[i][j][r] + bv);
        }
      }
  }
}

// ---------------- fused MLP kernel B: L3 + L4 ----------------
// out[M,128] = tanh(h2 @ wt2^T + b2) @ wt3^T + b3
// L4 accumulator (4x4 f32x4) persists across the 4 jb col-blocks of h3.
__global__ __launch_bounds__(256, 2) void mlp_b(
    const f16* __restrict__ h2, const f16* __restrict__ wt2,
    const f16* __restrict__ wt3, const float* __restrict__ b2,
    const float* __restrict__ b3, float* __restrict__ out, int M) {
  __shared__ __align__(16) char H3[128 * 256];  // 32KB swizzled f16 [128][128]

  const int tid = threadIdx.x;
  const int lane = tid & 63, wid = tid >> 6;
  const int wm = wid & 1, wn = wid >> 1;
  const int lr = lane & 15, lq = lane >> 4;
  const long long m0 = (long long)blockIdx.x * 128;

  f32x4 oacc[4][4];
#pragma unroll
  for (int i = 0; i < 4; ++i)
#pragma unroll
    for (int j = 0; j < 4; ++j)
#pragma unroll
      for (int r = 0; r < 4; ++r) oacc[i][j][r] = 0.0f;

#pragma unroll 1
  for (int jb = 0; jb < 4; ++jb) {
    // L3 col-block: h3jb = tanh(h2 @ wt2[jb]^T + b2[jb])  (128x128)
    f32x4 acc[4][4];
#pragma unroll
    for (int i = 0; i < 4; ++i)
#pragma unroll
      for (int j = 0; j < 4; ++j)
#pragma unroll
        for (int r = 0; r < 4; ++r) acc[i][j][r] = 0.0f;

#pragma unroll 2
    for (int k0 = 0; k0 < 512; k0 += 32) {
      f16x8 a[4], b[4];
#pragma unroll
      for (int i = 0; i < 4; ++i)
        a[i] = *reinterpret_cast<const f16x8*>(
            h2 + (m0 + wm * 64 + i * 16 + lr) * 512 + k0 + lq * 8);
#pragma unroll
      for (int j = 0; j < 4; ++j)
        b[j] = *reinterpret_cast<const f16x8*>(
            wt2 + (jb * 128 + wn * 64 + j * 16 + lr) * 512 + k0 + lq * 8);
#pragma unroll
      for (int i = 0; i < 4; ++i)
#pragma unroll
        for (int j = 0; j < 4; ++j)
          acc[i][j] = __builtin_amdgcn_mfma_f32_16x16x32_f16(a[i], b[j], acc[i][j], 0, 0, 0);
    }
#pragma unroll
    for (int i = 0; i < 4; ++i)
#pragma unroll
      for (int j = 0; j < 4; ++j) {
        int col = wn * 64 + j * 16 + lr;
        float bv = b2[jb * 128 + col];
#pragma unroll
        for (int r = 0; r < 4; ++r) {
          int row = wm * 64 + i * 16 + lq * 4 + r;
          *reinterpret_cast<f16*>(H3 + swz(row, col * 2)) =
              (f16)fast_tanh(acc[i][j][r] + bv);
        }
      }
    __syncthreads();

    // L4 partial: oacc += h3jb @ wt3[:, jb*128 .. +127]^T
#pragma unroll
    for (int k0 = 0; k0 < 128; k0 += 32) {
      f16x8 a[4], b[4];
#pragma unroll
      for (int i = 0; i < 4; ++i)
        a[i] = *reinterpret_cast<const f16x8*>(
            H3 + swz(wm * 64 + i * 16 + lr, (k0 + lq * 8) * 2));
#pragma unroll
      for (int j = 0; j < 4; ++j)
        b[j] = *reinterpret_cast<const f16x8*>(
            wt3 + (wn * 64 + j * 16 + lr) * 512 + jb * 128 + k0 + lq * 8);
#pragma unroll
      for (int i = 0; i < 4; ++i)
#pragma unroll
        for (int j = 0; j < 4; ++j)
          oacc[i][j] = __builtin_amdgcn_mfma_f32_16x16x32_f16(a[i], b[j], oacc[i][j], 0, 0, 0);
    }
    __syncthreads();
  }

  // epilogue: out = oacc + b3 (f32), masked to valid rows
#pragma unroll
  for (int i = 0; i < 4; ++i)
#pragma unroll
    for (int j = 0; j < 4; ++j) {
      int col = wn * 64 + j * 16 + lr;
      float bv = b3[col];
#pragma unroll
      for (int r = 0; r < 4; ++r) {
        long long row = m0 + wm * 64 + i * 16 + lq * 4 + r;
        if (row < M) out[row * 128 + col] = oacc[i][j][r] + bv;
      }
    }
}

extern "C" void kernel_launch(void* const* d_in, const int* in_sizes, int n_in,
                              void* d_out, int out_size, void* d_ws, size_t ws_size,
                              hipStream_t stream) {
  const float* z  = (const float*)d_in[0];
  const int*   ei = (const int*)d_in[1];
  const float* Wg = (const float*)d_in[2];
  const float* Ws = (const float*)d_in[3];
  const float* bg = (const float*)d_in[4];
  const float* W1 = (const float*)d_in[5];
  const float* b1 = (const float*)d_in[6];
  const float* W2 = (const float*)d_in[7];
  const float* b2 = (const float*)d_in[8];
  const float* W3 = (const float*)d_in[9];
  const float* b3 = (const float*)d_in[10];

  const int Nn = in_sizes[0] / 128;
  const int E  = in_sizes[1] / 2;
  const int* src = ei;
  const int* dst = ei + E;
  const int nb = (Nn + 1023) / 1024;
  const int gm = (Nn + 127) / 128;
  const long long Mpad = (long long)gm * 128;

  // workspace layout (no overlays needed; peak ~160 MB):
  //   Xc (Mpad x 256 f16), CSR arrays, h2 (Mpad x 512 f16), weights
  char* base = (char*)d_ws;
  size_t off = 0;
  auto alloc = [&](size_t b) -> void* {
    void* p = base + off;
    off += (b + 255) & ~(size_t)255;
    return p;
  };
  f16* Xc        = (f16*)alloc((size_t)Mpad * 256 * 2);
  int* degi      = (int*)alloc((size_t)Nn * 4);
  int* row_start = (int*)alloc((size_t)(Nn + 1) * 4);
  int* cursor    = (int*)alloc((size_t)Nn * 4);
  int* adj       = (int*)alloc((size_t)E * 4);
  int* bsum      = (int*)alloc((size_t)nb * 4);
  int* boff      = (int*)alloc((size_t)nb * 4);
  f16* h2        = (f16*)alloc((size_t)Mpad * 512 * 2);
  f16* wgs       = (f16*)alloc((size_t)128 * 256 * 2);
  f16* wt1       = (f16*)alloc((size_t)512 * 128 * 2);
  f16* wt2       = (f16*)alloc((size_t)512 * 512 * 2);
  f16* wt3       = (f16*)alloc((size_t)128 * 512 * 2);

  // CSR build
  zero_kernel<<<(Nn + 255) / 256, 256, 0, stream>>>(degi, Nn);
  deg_count<<<(E + 255) / 256, 256, 0, stream>>>(dst, degi, E);
  scan_partial<<<nb, 256, 0, stream>>>(degi, bsum, Nn);
  scan_bsums<<<1, 64, 0, stream>>>(bsum, boff, row_start, nb, Nn);
  scan_final<<<nb, 256, 0, stream>>>(degi, boff, row_start, cursor, Nn);
  fill_adj<<<(E + 255) / 256, 256, 0, stream>>>(src, dst, cursor, adj, E);

  // weight prep
  build_wgs<<<(128 * 256 + 255) / 256, 256, 0, stream>>>(Wg, Ws, wgs);
  transpose_cast<<<(128 * 512 + 255) / 256, 256, 0, stream>>>(W1, wt1, 128, 512);
  transpose_cast<<<(512 * 512 + 255) / 256, 256, 0, stream>>>(W2, wt2, 512, 512);
  transpose_cast<<<(512 * 128 + 255) / 256, 256, 0, stream>>>(W3, wt3, 512, 128);

  // gather + Xcat
  {
    long long tot = (long long)Nn * 64;
    gather_xcat<<<(int)((tot + 255) / 256), 256, 0, stream>>>(z, row_start, adj, Xc, Nn);
  }

  // fused MLP
  mlp_a<<<gm, 256, 0, stream>>>(Xc, wgs, wt1, bg, b1, h2);
  mlp_b<<<gm, 256, 0, stream>>>(h2, wt2, wt3, b2, b3, (float*)d_out, Nn);
}

// Round 5
// 393.802 us; speedup vs baseline: 1.4681x; 1.4681x over previous
//
#include <hip/hip_runtime.h>
#include <hip/hip_fp16.h>

// GDE func: out = MLP(relu(mean_agg(z,edges)@Wg + z@Ws + bg))
// Round 4 -> 5: revert fused direct-global MLP (latency-bound, 8% MfmaUtil).
// Back to separate GEMMs with global_load_lds staging, but BN=256 / 8 waves
// for the 512-col layers (wave tile 64x64 = m97 MFMA:ds ratio, 2 col passes
// over h2 instead of 8). Gather: 4-way unrolled independent load chains.

typedef _Float16 f16;
typedef __attribute__((ext_vector_type(2))) _Float16 f16x2;
typedef __attribute__((ext_vector_type(8))) _Float16 f16x8;
typedef __attribute__((ext_vector_type(4))) float f32x4;

__device__ __forceinline__ void async_load16(const void* g, void* lds) {
  __builtin_amdgcn_global_load_lds(
      (const __attribute__((address_space(1))) void*)g,
      (__attribute__((address_space(3))) void*)lds, 16, 0, 0);
}

__device__ __forceinline__ float fast_tanh(float x) {
  float a = fabsf(x);
  float e = __expf(-2.0f * a);
  float r = (1.0f - e) * __builtin_amdgcn_rcpf(1.0f + e);
  return copysignf(r, x);
}

__global__ __launch_bounds__(256) void zero_kernel(int* __restrict__ p, int n) {
  int i = blockIdx.x * 256 + threadIdx.x;
  int stride = gridDim.x * 256;
  for (; i < n; i += stride) p[i] = 0;
}

// ---- CSR build ----
__global__ __launch_bounds__(256) void deg_count(const int* __restrict__ dst,
                                                 int* __restrict__ degi, int E) {
  int e = blockIdx.x * 256 + threadIdx.x;
  if (e < E) atomicAdd(&degi[dst[e]], 1);
}

__global__ __launch_bounds__(256) void scan_partial(const int* __restrict__ degi,
                                                    int* __restrict__ bsum, int N) {
  __shared__ int lds[256];
  int b = blockIdx.x, t = threadIdx.x;
  int s = 0;
#pragma unroll
  for (int j = 0; j < 4; ++j) {
    int idx = b * 1024 + t * 4 + j;
    if (idx < N) s += degi[idx];
  }
  lds[t] = s;
  __syncthreads();
  for (int off = 128; off > 0; off >>= 1) {
    if (t < off) lds[t] += lds[t + off];
    __syncthreads();
  }
  if (t == 0) bsum[b] = lds[0];
}

__global__ void scan_bsums(const int* __restrict__ bsum, int* __restrict__ boff,
                           int* __restrict__ row_start, int nb, int N) {
  if (threadIdx.x == 0 && blockIdx.x == 0) {
    int acc = 0;
    for (int i = 0; i < nb; ++i) { boff[i] = acc; acc += bsum[i]; }
    row_start[N] = acc;  // == E
  }
}

__global__ __launch_bounds__(256) void scan_final(
    const int* __restrict__ degi, const int* __restrict__ boff,
    int* __restrict__ row_start, int* __restrict__ cursor, int N) {
  __shared__ int lds[256];
  int b = blockIdx.x, t = threadIdx.x;
  int base = b * 1024;
  int v[4];
  int s = 0;
#pragma unroll
  for (int j = 0; j < 4; ++j) {
    int idx = base + t * 4 + j;
    v[j] = (idx < N) ? degi[idx] : 0;
    s += v[j];
  }
  lds[t] = s;
  __syncthreads();
  for (int off = 1; off < 256; off <<= 1) {
    int x = lds[t];
    int y = (t >= off) ? lds[t - off] : 0;
    __syncthreads();
    lds[t] = x + y;
    __syncthreads();
  }
  int pre = boff[b] + lds[t] - s;
#pragma unroll
  for (int j = 0; j < 4; ++j) {
    int idx = base + t * 4 + j;
    if (idx < N) { row_start[idx] = pre; cursor[idx] = pre; pre += v[j]; }
  }
}

__global__ __launch_bounds__(256) void fill_adj(const int* __restrict__ src,
                                                const int* __restrict__ dst,
                                                int* __restrict__ cursor,
                                                int* __restrict__ adj, int E) {
  int e = blockIdx.x * 256 + threadIdx.x;
  if (e >= E) return;
  int p = atomicAdd(&cursor[dst[e]], 1);
  adj[p] = src[e];
}

// ---- fused gather + mean + Xcat: one 64-lane wave per node ----
// lane covers cols {2*lane, 2*lane+1} via float2; 4 independent neighbor
// chains hide the adj->z dependent-load latency.
__global__ __launch_bounds__(256) void gather_xcat(
    const float* __restrict__ z, const int* __restrict__ row_start,
    const int* __restrict__ adj, f16* __restrict__ Xc, int N) {
  int wave = (blockIdx.x * 256 + threadIdx.x) >> 6;
  int lane = threadIdx.x & 63;
  if (wave >= N) return;
  int n = wave;
  int beg = row_start[n], end = row_start[n + 1];
  float sx = 0.0f, sy = 0.0f;
  float s1x = 0.0f, s1y = 0.0f, s2x = 0.0f, s2y = 0.0f, s3x = 0.0f, s3y = 0.0f;
  int i = beg;
  for (; i + 4 <= end; i += 4) {
    int n0 = adj[i], n1 = adj[i + 1], n2 = adj[i + 2], n3 = adj[i + 3];
    float2 v0 = *(const float2*)(z + (long long)n0 * 128 + 2 * lane);
    float2 v1 = *(const float2*)(z + (long long)n1 * 128 + 2 * lane);
    float2 v2 = *(const float2*)(z + (long long)n2 * 128 + 2 * lane);
    float2 v3 = *(const float2*)(z + (long long)n3 * 128 + 2 * lane);
    sx += v0.x; sy += v0.y;
    s1x += v1.x; s1y += v1.y;
    s2x += v2.x; s2y += v2.y;
    s3x += v3.x; s3y += v3.y;
  }
  for (; i < end; ++i) {
    float2 v = *(const float2*)(z + (long long)adj[i] * 128 + 2 * lane);
    sx += v.x; sy += v.y;
  }
  sx += s1x + s2x + s3x;
  sy += s1y + s2y + s3y;
  int dg = end - beg;
  float inv = 1.0f / (float)(dg > 1 ? dg : 1);
  long long o = (long long)n * 256;
  f16x2 m; m[0] = (f16)(sx * inv); m[1] = (f16)(sy * inv);
  *(f16x2*)(Xc + o + 2 * lane) = m;
  float2 zv = *(const float2*)(z + (long long)n * 128 + 2 * lane);
  f16x2 zc; zc[0] = (f16)zv.x; zc[1] = (f16)zv.y;
  *(f16x2*)(Xc + o + 128 + 2 * lane) = zc;
}

// ---- weight prep (Wt stored [col][K] row-major f16) ----
__global__ __launch_bounds__(256) void build_wgs(
    const float* __restrict__ Wg, const float* __restrict__ Ws, f16* __restrict__ Wt) {
  int i = blockIdx.x * 256 + threadIdx.x;
  if (i >= 128 * 256) return;
  int n = i >> 8, k = i & 255;
  float v = (k < 128) ? Wg[k * 128 + n] : Ws[(k - 128) * 128 + n];
  Wt[i] = (f16)v;
}

__global__ __launch_bounds__(256) void transpose_cast(
    const float* __restrict__ W, f16* __restrict__ Wt, int K, int N) {
  int i = blockIdx.x * 256 + threadIdx.x;
  if (i >= K * N) return;
  int n = i / K, k = i - n * K;
  Wt[i] = (f16)W[k * N + n];
}

// ---------------- MFMA GEMM, BM=128 x BN(128|256), BK=64 ----------------
// C[M,NOUT] = act(X[M,K] @ Wt^T + bias); Wt is [NOUT][K] f16.
// Waves: 2 x (BN/64), each wave 64x64 output = 4x4 frags of 16x16x32
// (m97 MFMA:ds-byte ratio). Staging: global_load_lds 16B/lane into linear
// LDS; chunk q = 8 rows (1KiB). X needs Mpad >= grid.x*128 rows allocated.
template <int K, int NOUT, int BN, int ACT, bool OUTF32>
__global__ __launch_bounds__(128 * (BN / 64)) void gemm_t(
    const f16* __restrict__ X, const f16* __restrict__ Wt,
    const float* __restrict__ bias, void* __restrict__ OutV, int M) {
  constexpr int WC = BN / 64;            // wave-grid cols
  constexpr int NWAVE = 2 * WC;          // 4 or 8 waves
  constexpr int CX = 16 / NWAVE;         // X chunks per wave (4 or 2)
  constexpr int CW = (BN / 8) / NWAVE;   // W chunks per wave (4)
  __shared__ __align__(16) f16 Xs[128 * 64];
  __shared__ __align__(16) f16 Wsh[BN * 64];

  const int tid = threadIdx.x;
  const int wid = tid >> 6, lane = tid & 63;
  const int wm = wid & 1, wn = wid >> 1;           // wn in [0, WC)
  const int lr = lane & 15, lq = lane >> 4;
  const long long m0 = (long long)blockIdx.x * 128;
  const int n0 = blockIdx.y * BN;

  f32x4 acc[4][4];
#pragma unroll
  for (int i = 0; i < 4; ++i)
#pragma unroll
    for (int j = 0; j < 4; ++j)
#pragma unroll
      for (int r = 0; r < 4; ++r) acc[i][j][r] = 0.0f;

  const int srow = lane >> 3;        // 0..7 within chunk
  const int scol = (lane & 7) * 8;   // f16 col in K-slice
  const f16* Xg = X + m0 * K;
  const f16* Wg = Wt + (long long)n0 * K;

  for (int k0 = 0; k0 < K; k0 += 64) {
#pragma unroll
    for (int c = 0; c < CX; ++c) {
      int q = wid * CX + c;          // 8-row chunk of X tile
      async_load16(Xg + (long long)(q * 8 + srow) * K + k0 + scol, &Xs[q * 512]);
    }
#pragma unroll
    for (int c = 0; c < CW; ++c) {
      int q = wid * CW + c;          // 8-row chunk of W tile
      async_load16(Wg + (long long)(q * 8 + srow) * K + k0 + scol, &Wsh[q * 512]);
    }
    __syncthreads();
#pragma unroll
    for (int kk = 0; kk < 64; kk += 32) {
      f16x8 a[4], b[4];
#pragma unroll
      for (int i = 0; i < 4; ++i) {
        a[i] = *reinterpret_cast<const f16x8*>(&Xs[(wm * 64 + i * 16 + lr) * 64 + kk + lq * 8]);
        b[i] = *reinterpret_cast<const f16x8*>(&Wsh[(wn * 64 + i * 16 + lr) * 64 + kk + lq * 8]);
      }
#pragma unroll
      for (int i = 0; i < 4; ++i)
#pragma unroll
        for (int j = 0; j < 4; ++j)
          acc[i][j] = __builtin_amdgcn_mfma_f32_16x16x32_f16(a[i], b[j], acc[i][j], 0, 0, 0);
    }
    __syncthreads();
  }

#pragma unroll
  for (int i = 0; i < 4; ++i) {
#pragma unroll
    for (int j = 0; j < 4; ++j) {
      int col = n0 + wn * 64 + j * 16 + lr;
      float bv = bias[col];
#pragma unroll
      for (int r = 0; r < 4; ++r) {
        long long row = m0 + wm * 64 + i * 16 + lq * 4 + r;
        if (row < M) {
          float v = acc[i][j][r] + bv;
          if (ACT == 1) v = fmaxf(v, 0.0f);
          else if (ACT == 2) v = fast_tanh(v);
          if constexpr (OUTF32)
            ((float*)OutV)[row * NOUT + col] = v;
          else
            ((f16*)OutV)[row * NOUT + col] = (f16)v;
        }
      }
    }
  }
}

extern "C" void kernel_launch(void* const* d_in, const int* in_sizes, int n_in,
                              void* d_out, int out_size, void* d_ws, size_t ws_size,
                              hipStream_t stream) {
  const float* z  = (const float*)d_in[0];
  const int*   ei = (const int*)d_in[1];
  const float* Wg = (const float*)d_in[2];
  const float* Ws = (const float*)d_in[3];
  const float* bg = (const float*)d_in[4];
  const float* W1 = (const float*)d_in[5];
  const float* b1 = (const float*)d_in[6];
  const float* W2 = (const float*)d_in[7];
  const float* b2 = (const float*)d_in[8];
  const float* W3 = (const float*)d_in[9];
  const float* b3 = (const float*)d_in[10];

  const int Nn = in_sizes[0] / 128;
  const int E  = in_sizes[1] / 2;
  const int* src = ei;
  const int* dst = ei + E;
  const int nb = (Nn + 1023) / 1024;
  const int gm = (Nn + 127) / 128;
  const long long Mpad = (long long)gm * 128;

  // workspace overlay (peak ~207 MB):
  //   [0, 51.2M)        Xc   (gather -> gemm1)
  //   [51.2, 76.8M)     h1   (gemm1 -> gemm2)
  //   [76.8, ~80.5M)    CSR  (build -> gather)
  //   [0, 102.4M)       h3   (gemm3 -> gemm4; overlays Xc,h1,CSR - all dead)
  //   [102.4, 204.8M)   h2   (gemm2 -> gemm3)
  //   [204.8M, ...)     prepped weights (~1.7 MB)
  char* base = (char*)d_ws;
  const size_t XCB  = (size_t)Mpad * 256 * 2;   // 51.2 MB
  const size_t H1B  = (size_t)Mpad * 128 * 2;   // 25.6 MB
  const size_t H3B  = (size_t)Mpad * 512 * 2;   // 102.4 MB
  f16* Xc = (f16*)(base);
  f16* h1 = (f16*)(base + XCB);
  f16* h3 = (f16*)(base);
  size_t off = XCB + H1B;
  auto alloc = [&](size_t b) -> void* {
    void* p = base + off;
    off += (b + 255) & ~(size_t)255;
    return p;
  };
  int* degi      = (int*)alloc((size_t)Nn * 4);
  int* row_start = (int*)alloc((size_t)(Nn + 1) * 4);
  int* cursor    = (int*)alloc((size_t)Nn * 4);
  int* adj       = (int*)alloc((size_t)E * 4);
  int* bsum      = (int*)alloc((size_t)nb * 4);
  int* boff      = (int*)alloc((size_t)nb * 4);
  off = H3B;  // h2 starts after h3 span
  f16* h2  = (f16*)alloc((size_t)Mpad * 512 * 2);
  f16* wgs = (f16*)alloc((size_t)128 * 256 * 2);
  f16* wt1 = (f16*)alloc((size_t)512 * 128 * 2);
  f16* wt2 = (f16*)alloc((size_t)512 * 512 * 2);
  f16* wt3 = (f16*)alloc((size_t)128 * 512 * 2);

  // CSR build
  zero_kernel<<<(Nn + 255) / 256, 256, 0, stream>>>(degi, Nn);
  deg_count<<<(E + 255) / 256, 256, 0, stream>>>(dst, degi, E);
  scan_partial<<<nb, 256, 0, stream>>>(degi, bsum, Nn);
  scan_bsums<<<1, 64, 0, stream>>>(bsum, boff, row_start, nb, Nn);
  scan_final<<<nb, 256, 0, stream>>>(degi, boff, row_start, cursor, Nn);
  fill_adj<<<(E + 255) / 256, 256, 0, stream>>>(src, dst, cursor, adj, E);

  // weight prep
  build_wgs<<<(128 * 256 + 255) / 256, 256, 0, stream>>>(Wg, Ws, wgs);
  transpose_cast<<<(128 * 512 + 255) / 256, 256, 0, stream>>>(W1, wt1, 128, 512);
  transpose_cast<<<(512 * 512 + 255) / 256, 256, 0, stream>>>(W2, wt2, 512, 512);
  transpose_cast<<<(512 * 128 + 255) / 256, 256, 0, stream>>>(W3, wt3, 512, 128);

  // gather + Xcat
  {
    long long tot = (long long)Nn * 64;
    gather_xcat<<<(int)((tot + 255) / 256), 256, 0, stream>>>(z, row_start, adj, Xc, Nn);
  }

  // GEMMs: L1 (K=256,N=128), L2 (K=128,N=512), L3 (K=512,N=512), L4 (K=512,N=128)
  gemm_t<256, 128, 128, 1, false><<<dim3(gm, 1), 256, 0, stream>>>(Xc, wgs, bg, (void*)h1, Nn);
  gemm_t<128, 512, 256, 2, false><<<dim3(gm, 2), 512, 0, stream>>>(h1, wt1, b1, (void*)h2, Nn);
  gemm_t<512, 512, 256, 2, false><<<dim3(gm, 2), 512, 0, stream>>>(h2, wt2, b2, (void*)h3, Nn);
  gemm_t<512, 128, 128, 0, true><<<dim3(gm, 1), 256, 0, stream>>>(h3, wt3, b3, d_out, Nn);
}